// Round 2
// baseline (179.695 us; speedup 1.0000x reference)
//
#include <hip/hip_runtime.h>
#include <hip/hip_bf16.h>
#include <math.h>

#define BB 4
#define TT 12
#define NN 2000
#define KK 8
#define CC 32
#define EPSF 1e-5f
#define LISTCAP 16
#define NSITES (BB * TT * NN)   // 96000

typedef unsigned short u16;
typedef __bf16 bf16x8 __attribute__((ext_vector_type(8)));
typedef float  f32x4  __attribute__((ext_vector_type(4)));

__device__ __forceinline__ u16 f2bf(float x) {
    union { __hip_bfloat16 h; u16 u; } c;
    c.h = __float2bfloat16(x);   // RNE
    return c.u;
}
__device__ __forceinline__ float bf2f(u16 u) {
    return __uint_as_float(((unsigned)u) << 16);
}
__device__ __forceinline__ float mask6(float v) {
    if (isnan(v)) v = 6.0f;
    if (isinf(v)) v = 0.0f;
    return fminf(v, 6.0f);
}

// ---------------------------------------------------------------------------
// Kernel A (R12, validated): block-per-row, value-only 32-bit top-8.
// thr = 8th-largest VALUE; downstream needs only the SET {v > thr} plus
// lowest-index ties at v == thr. 4 waves/row, per-lane sort-8 network,
// float butterfly merge, register-resident pass 2.
// ---------------------------------------------------------------------------
__global__ __launch_bounds__(256)
void topk_prep(const float* __restrict__ adj, const float* __restrict__ adjm,
               int* __restrict__ t_idx, float* __restrict__ t_val,
               int* __restrict__ t_cnt, float* __restrict__ t_deg,
               float* __restrict__ t_ideg, float2* __restrict__ t_sc)
{
    __shared__ float sTop[4][8];
    __shared__ float sDeg[4];
    __shared__ int   sCp[4];
    __shared__ int   sStrictIdx[8];
    __shared__ float sStrictVal[8];
    __shared__ int   sTieIdx[16];
    __shared__ int   nStrict, nTie;
    __shared__ float sThr;

    const int tid  = threadIdx.x;
    const int lane = tid & 63;
    const int wid  = tid >> 6;

    const int grow = blockIdx.x;                    // 0..3999, one row per block
    const int mat = (grow >= NN) ? 1 : 0;           // 0 = adj_mask, 1 = adj
    const int row = grow - mat * NN;
    const float* src = (mat == 0 ? adjm : adj) + (size_t)row * NN;
    const float4* src4 = (const float4*)src;        // 500 float4 per row

    if (tid == 0) { nStrict = 0; nTie = 0; }

    // ---- load: 2 coalesced float4 per thread (2048 >= 2000 slots) ----
    // values are uniform [0,1): -1.0f is a safe "below everything" sentinel.
    const float4 v0 = src4[tid];                    // idx4 = tid < 500 always
    const float4 v1 = (tid < 244) ? src4[256 + tid]
                                  : make_float4(-1.f, -1.f, -1.f, -1.f);
    const float vv[8] = {v0.x, v0.y, v0.z, v0.w, v1.x, v1.y, v1.z, v1.w};

    // ---- per-lane sort-8 descending: Batcher 19-comparator network ----
    float a[8];
    #pragma unroll
    for (int j = 0; j < 8; ++j) a[j] = vv[j];
    #define CE(i, j) { float _mx = fmaxf(a[i], a[j]); float _mn = fminf(a[i], a[j]); a[i] = _mx; a[j] = _mn; }
    CE(0,1) CE(2,3) CE(4,5) CE(6,7)
    CE(0,2) CE(1,3) CE(4,6) CE(5,7)
    CE(1,2) CE(5,6)
    CE(0,4) CE(1,5) CE(2,6) CE(3,7)
    CE(2,4) CE(3,5)
    CE(1,2) CE(3,4) CE(5,6)
    #undef CE

    // ---- wave butterfly merge: 6 levels, 32-bit values ----
    float key[8];
    #pragma unroll
    for (int j = 0; j < 8; ++j) key[j] = a[j];
    #pragma unroll
    for (int d = 1; d < 64; d <<= 1) {
        float ok[8], c[8];
        #pragma unroll
        for (int j = 0; j < 8; ++j) ok[j] = __shfl_xor(key[j], d, 64);
        #pragma unroll
        for (int j = 0; j < 8; ++j) c[j] = fmaxf(key[j], ok[7 - j]);
        #pragma unroll
        for (int st = 4; st >= 1; st >>= 1) {
            #pragma unroll
            for (int j = 0; j < 8; ++j) {
                if ((j & st) == 0 && (j | st) < 8) {
                    float hi = fmaxf(c[j], c[j | st]);
                    float lo = fminf(c[j], c[j | st]);
                    c[j] = hi; c[j | st] = lo;
                }
            }
        }
        #pragma unroll
        for (int j = 0; j < 8; ++j) key[j] = c[j];
    }
    if (lane == 0) {
        #pragma unroll
        for (int j = 0; j < 8; ++j) sTop[wid][j] = key[j];
    }
    __syncthreads();

    // ---- thr: 4-way merge of sorted 8-lists, 8 steps (thread 0) ----
    if (tid == 0) {
        int p0 = 0, p1 = 0, p2 = 0, p3 = 0;
        float t = -1.f;
        for (int r = 0; r < 8; ++r) {
            const float c0 = (p0 < 8) ? sTop[0][p0] : -2.f;
            const float c1 = (p1 < 8) ? sTop[1][p1] : -2.f;
            const float c2 = (p2 < 8) ? sTop[2][p2] : -2.f;
            const float c3 = (p3 < 8) ? sTop[3][p3] : -2.f;
            float bv = c0; int best = 0;
            if (c1 > bv) { bv = c1; best = 1; }
            if (c2 > bv) { bv = c2; best = 2; }
            if (c3 > bv) { bv = c3; best = 3; }
            if (best == 0) ++p0; else if (best == 1) ++p1;
            else if (best == 2) ++p2; else ++p3;
            t = bv;
        }
        sThr = t;
    }
    __syncthreads();
    const float thr = sThr;

    // ---- pass 2: from registers. deg/cp over ALL v >= thr; collect set ----
    float degp = 0.f; int cp = 0;
    #pragma unroll
    for (int s = 0; s < 8; ++s) {
        const float v = vv[s];
        const int e = (s < 4) ? (tid * 4 + s) : ((256 + tid) * 4 + (s - 4));
        const bool ge = (v >= thr);
        degp += ge ? v : 0.f;
        cp   += (ge && v > 0.f) ? 1 : 0;
        if (v > thr) {                               // <= 7 per row
            int p = atomicAdd(&nStrict, 1);
            if (p < 8) { sStrictIdx[p] = e; sStrictVal[p] = v; }
        } else if (v == thr) {                       // ties (bit-exact equality)
            int p = atomicAdd(&nTie, 1);
            if (p < 16) sTieIdx[p] = e;
        }
    }
    #pragma unroll
    for (int off = 32; off >= 1; off >>= 1) {
        degp += __shfl_xor(degp, off, 64);
        cp   += __shfl_xor(cp, off, 64);
    }
    if (lane == 0) { sDeg[wid] = degp; sCp[wid] = cp; }
    __syncthreads();

    // ---- finalize (thread 0): lowest-index ties complete the top-8 set ----
    if (tid == 0) {
        const float deg = sDeg[0] + sDeg[1] + sDeg[2] + sDeg[3];
        const int cnt_pos = sCp[0] + sCp[1] + sCp[2] + sCp[3];
        int m = nStrict; if (m > 8) m = 8;           // mathematically <= 7
        int nt = nTie;   if (nt > 16) nt = 16;
        // insertion-sort tie indices ascending (nt is tiny, usually 1)
        for (int i = 1; i < nt; ++i) {
            int v = sTieIdx[i]; int j = i - 1;
            while (j >= 0 && sTieIdx[j] > v) { sTieIdx[j + 1] = sTieIdx[j]; --j; }
            sTieIdx[j + 1] = v;
        }
        const size_t ob = (size_t)grow * LISTCAP;
        for (int j = 0; j < m; ++j) {
            t_idx[ob + j] = sStrictIdx[j];
            t_val[ob + j] = sStrictVal[j];
        }
        const int need = 8 - m;                      // >= 1; nt >= need always
        for (int j = 0; j < need; ++j) {
            t_idx[ob + m + j] = sTieIdx[j];
            t_val[ob + m + j] = thr;
        }
        int extra = nt - need;
        if (extra > 8) extra = 8; if (extra < 0) extra = 0;
        for (int j = 0; j < extra; ++j) {
            t_idx[ob + 8 + j] = sTieIdx[need + j];
            t_val[ob + 8 + j] = thr;
        }
        t_cnt[grow]  = 8 + extra;
        t_deg[grow]  = deg;
        t_ideg[grow] = 1.0f / deg;
        const float s1 = log1pf((float)cnt_pos);
        t_sc[grow]   = make_float2(s1, 1.0f / s1);
    }
}

// ---------------------------------------------------------------------------
// Kernel B: stower0 + tcn0 (blocks 0..374) + weight-plane prep (375..387).
// Unchanged from R9 (validated; Theta planes pre-swizzled).
// ---------------------------------------------------------------------------
__global__ __launch_bounds__(256)
void stower0_tcn0(const float* __restrict__ X,
                  const int* __restrict__ t_idx, const float* __restrict__ t_val,
                  const int* __restrict__ t_cnt, const float* __restrict__ t_deg,
                  const float* __restrict__ Theta0, const float* __restrict__ bias0,
                  const float* __restrict__ Wt0, const float* __restrict__ bt0,
                  const float* __restrict__ Theta1, const float* __restrict__ Wt1,
                  u16* __restrict__ thHi, u16* __restrict__ thLo,
                  u16* __restrict__ wtHi, u16* __restrict__ wtLo,
                  float* __restrict__ I1)
{
    const int tid = threadIdx.x;
    if (blockIdx.x >= NSITES / 256) {
        const int pb = blockIdx.x - NSITES / 256;   // 0..12
        if (pb < 12) {                              // Theta1: 12288 elems
            const int base = pb * 1024;
            #pragma unroll
            for (int t = 0; t < 4; ++t) {
                const int i = base + t * 256 + tid;
                const int r = i >> 5, o = i & 31;
                const int jm = r >> 7, k = r & 127;
                const int tile = jm * 2 + (o >> 4), n = o & 15;
                const float v = Theta1[i];
                const u16 hi = f2bf(v);
                const int idx = (tile * 16 + n) * 128 + (((k >> 3) ^ n) << 3) + (k & 7);
                thHi[idx] = hi;
                thLo[idx] = f2bf(v - bf2f(hi));
            }
        } else {                                    // Wt1: 1024 elems
            #pragma unroll
            for (int t = 0; t < 4; ++t) {
                const int i = t * 256 + tid;
                const float v = Wt1[i];
                const u16 hi = f2bf(v);
                wtHi[i] = hi;
                wtLo[i] = f2bf(v - bf2f(hi));
            }
        }
        return;
    }

    const int site = blockIdx.x * 256 + tid;
    const int n  = site % NN;
    const int bt = site / NN;
    const float* xrow = X + (size_t)bt * NN;

    const size_t base = (size_t)n * LISTCAP;
    const int cnt   = t_cnt[n];
    const float deg = t_deg[n];
    float wsum = 0.f, wsq = 0.f, mx = -INFINITY, mn = INFINITY;
    for (int j = 0; j < cnt; ++j) {
        int   id = t_idx[base + j];
        float w  = t_val[base + j];
        float xv = xrow[id];
        wsum = fmaf(w, xv, wsum);
        wsq  = fmaf(w * xv, xv, wsq);
        if (j < KK && w > 0.f) { mx = fmaxf(mx, xv); mn = fminf(mn, xv); }
    }
    float mean = wsum / deg;
    float var  = wsq / deg - mean * mean;
    float sd   = sqrtf(fmaxf(var, 0.f) + EPSF);
    float m0 = mask6(mean), m1 = mask6(mx), m2 = mask6(mn), m3 = mask6(sd);

    float h0[CC];
    #pragma unroll
    for (int c = 0; c < CC; ++c) {
        float v = bias0[c];
        v = fmaf(m0, Theta0[0 * CC + c], v);
        v = fmaf(m1, Theta0[1 * CC + c], v);
        v = fmaf(m2, Theta0[2 * CC + c], v);
        v = fmaf(m3, Theta0[3 * CC + c], v);
        h0[c] = v;
    }
    float* op = I1 + (size_t)site * CC;
    #pragma unroll
    for (int c = 0; c < CC; ++c) {
        float acc = bt0[c] + h0[c];
        #pragma unroll
        for (int k = 0; k < CC; ++k) acc = fmaf(Wt0[c * CC + k], h0[k], acc);
        op[c] = tanhf(acc);
    }
}

// ---------------------------------------------------------------------------
// Kernel C (R13 fusion of C1+C2): stower1 agg + matmul + tcn1 + Wout.
// The 49 MB mHi/mLo HBM round-trip is eliminated: the aggregation (C1's
// exact math, bit-identical op order) now writes its swizzled A-frag
// layout DIRECTLY into the LDS m tile that phase 2 consumes, replacing
// the old phase-1 global->LDS memcpy. Sync structure preserved: agg
// writes occupy the same slot as the old staging writes (after the
// sPart sync, before the phase-2 sync), so the R4-validated aliasing
// discipline (mT / h regions in uSpace) is unchanged.
// ---------------------------------------------------------------------------
__global__ __launch_bounds__(256, 3)
void stower1_fused(const float* __restrict__ I1,
                   const int* __restrict__ t_idx, const float* __restrict__ t_val,
                   const int* __restrict__ t_cnt, const float* __restrict__ t_ideg,
                   const u16* __restrict__ thHi, const u16* __restrict__ thLo,
                   const u16* __restrict__ wtHi, const u16* __restrict__ wtLo,
                   const float2* __restrict__ t_sc,
                   const float* __restrict__ bias1, const float* __restrict__ bt1,
                   const float* __restrict__ Wout, const float* __restrict__ bout,
                   float* __restrict__ out)
{
    __shared__ u16 sBlo[96 * 128];                  // 24 KiB: Theta-lo (swizzled)
    __shared__ alignas(16) u16 uSpace[12288];       // 24 KiB: m tile | h
    __shared__ float sPart[64];

    u16*   mT  = uSpace;                            // m tile: [0..4095]=hi, [4096..8191]=lo
    u16*   hHi = uSpace;                            // 32*40 u16
    u16*   hLo = hHi + 32 * 40;
    float* h32 = (float*)((char*)uSpace + 5120);    // 32*33 f32

    const int tid  = threadIdx.x;
    const int lane = tid & 63;
    const int w    = tid >> 6;
    const int m15  = lane & 15;
    const int q    = lane >> 4;
    const int hf   = w & 1;          // phase-2 out-channel half
    const int st   = w >> 1;         // phase-2 site-tile 0..1
    const int ot   = w >> 1;         // phase-3 tcn out-tile
    const int st2  = w & 1;          // phase-3 site-tile

    // agg-phase role: group g (8 groups of 32) x feature f
    const int ag = tid >> 5;
    const int af = tid & 31;
    const int afh = af >> 3, afl = af & 7;

    // ---- init 1: memcpy thHi (24 KB, pre-swizzled) -> uSpace, extract ----
    for (int i = tid; i < 1536; i += 256)
        ((float4*)uSpace)[i] = ((const float4*)thHi)[i];
    __syncthreads();
    bf16x8 bH[3][4];
    #pragma unroll
    for (int j3 = 0; j3 < 3; ++j3) {
        const int tile = 2 * j3 + hf;
        #pragma unroll
        for (int ks = 0; ks < 4; ++ks)
            bH[j3][ks] = *(const bf16x8*)&uSpace[(tile * 16 + m15) * 128 +
                                                 (((ks * 4 + q) ^ m15) << 3)];
    }
    __syncthreads();
    // ---- init 2: memcpy thLo (pre-swizzled) -> sBlo; wt frags; scalars ----
    for (int i = tid; i < 1536; i += 256)
        ((float4*)sBlo)[i] = ((const float4*)thLo)[i];
    const bf16x8 bwh = *(const bf16x8*)&wtHi[(ot * 16 + m15) * 32 + q * 8];
    const bf16x8 bwl = *(const bf16x8*)&wtLo[(ot * 16 + m15) * 32 + q * 8];
    const float b1o   = bias1[hf * 16 + m15];
    const float bt1o  = bt1[ot * 16 + m15];
    const float wouto = Wout[ot * 16 + m15];
    const float boutv = bout[0];
    // no sync here: the sync after the first m-stage orders sBlo too.

    #pragma unroll 1
    for (int mb = 0; mb < 3; ++mb) {
        const int sbase = (blockIdx.x * 3 + mb) * 32;

        // ---- phase 1': aggregate 32 sites directly into LDS m tile ----
        // (C1's exact arithmetic and swizzled layout, LDS-local)
        #pragma unroll 1
        for (int r = 0; r < 4; ++r) {
            const int sl2  = ag * 4 + r;            // 0..31
            const int site = sbase + sl2;
            const int n    = site % NN;
            const int bt   = site / NN;
            const size_t rbase = (size_t)(NN + n) * LISTCAP;
            const int cnt    = t_cnt[NN + n];
            const float ideg = t_ideg[NN + n];
            const float* Ibt = I1 + (size_t)bt * NN * CC;

            const int4   i0 = *(const int4*)&t_idx[rbase];
            const int4   i1 = *(const int4*)&t_idx[rbase + 4];
            const float4 w0 = *(const float4*)&t_val[rbase];
            const float4 w1 = *(const float4*)&t_val[rbase + 4];

            const float x0 = Ibt[(size_t)i0.x * CC + af];
            const float x1 = Ibt[(size_t)i0.y * CC + af];
            const float x2 = Ibt[(size_t)i0.z * CC + af];
            const float x3 = Ibt[(size_t)i0.w * CC + af];
            const float x4 = Ibt[(size_t)i1.x * CC + af];
            const float x5 = Ibt[(size_t)i1.y * CC + af];
            const float x6 = Ibt[(size_t)i1.z * CC + af];
            const float x7 = Ibt[(size_t)i1.w * CC + af];

            float wsum = 0.f, wsq = 0.f, mx = -INFINITY, mn = INFINITY;
            #define AGG(wv, xv) do { \
                wsum = fmaf(wv, xv, wsum); wsq = fmaf(wv * xv, xv, wsq); \
                mx = fmaxf(mx, xv); mn = fminf(mn, xv); } while (0)
            AGG(w0.x, x0); AGG(w0.y, x1); AGG(w0.z, x2); AGG(w0.w, x3);
            AGG(w1.x, x4); AGG(w1.y, x5); AGG(w1.z, x6); AGG(w1.w, x7);
            #undef AGG
            if (cnt > 8) {                    // tie extras: ~never taken
                for (int j = 8; j < cnt; ++j) {
                    int   id = t_idx[rbase + j];
                    float wv = t_val[rbase + j];
                    float xv = Ibt[(size_t)id * CC + af];
                    wsum = fmaf(wv, xv, wsum);
                    wsq  = fmaf(wv * xv, xv, wsq);
                }
            }
            const float mean = wsum * ideg;
            const float var  = wsq * ideg - mean * mean;
            const float sd   = sqrtf(fmaxf(var, 0.f) + EPSF);

            const int sx = sl2 & 15;                // == site & 15 (sbase%32==0)
            const int b  = sl2 * 128;
            const int ia  = b + (((0  + afh) ^ sx) << 3) + afl;   // k = f
            const int ib  = b + (((4  + afh) ^ sx) << 3) + afl;   // k = 32+f
            const int ic  = b + (((8  + afh) ^ sx) << 3) + afl;   // k = 64+f
            const int id_ = b + (((12 + afh) ^ sx) << 3) + afl;   // k = 96+f
            u16 h0 = f2bf(mean); mT[ia]  = h0; mT[4096 + ia]  = f2bf(mean - bf2f(h0));
            u16 h1 = f2bf(mx);   mT[ib]  = h1; mT[4096 + ib]  = f2bf(mx   - bf2f(h1));
            u16 h2 = f2bf(mn);   mT[ic]  = h2; mT[4096 + ic]  = f2bf(mn   - bf2f(h2));
            u16 h3 = f2bf(sd);   mT[id_] = h3; mT[4096 + id_] = f2bf(sd   - bf2f(h3));
        }
        __syncthreads();

        // ---- phase 2: MFMA (A from LDS m tile, B hi regs / lo LDS) ----
        f32x4 acc[3];
        #pragma unroll
        for (int j3 = 0; j3 < 3; ++j3) acc[j3] = (f32x4){0.f, 0.f, 0.f, 0.f};
        const int arow = (st * 16 + m15) * 128;
        #pragma unroll
        for (int ks = 0; ks < 4; ++ks) {
            const int koff = (((ks * 4 + q) ^ m15) << 3);
            const bf16x8 aH = *(const bf16x8*)&mT[arow + koff];
            const bf16x8 aL = *(const bf16x8*)&mT[4096 + arow + koff];
            #pragma unroll
            for (int j3 = 0; j3 < 3; ++j3) {
                const bf16x8 bL = *(const bf16x8*)&sBlo[((2 * j3 + hf) * 16 + m15) * 128 + koff];
                acc[j3] = __builtin_amdgcn_mfma_f32_16x16x32_bf16(aH, bH[j3][ks], acc[j3], 0, 0, 0);
                acc[j3] = __builtin_amdgcn_mfma_f32_16x16x32_bf16(aH, bL,          acc[j3], 0, 0, 0);
                acc[j3] = __builtin_amdgcn_mfma_f32_16x16x32_bf16(aL, bH[j3][ks], acc[j3], 0, 0, 0);
            }
        }
        __syncthreads();   // all m-tile reads done -> safe to alias h

        // ---- combine scalers -> h (split-bf16 + f32 residual) ----
        #pragma unroll
        for (int r = 0; r < 4; ++r) {
            const int sl2  = st * 16 + q * 4 + r;
            const int site = sbase + sl2;
            const int n    = site % NN;
            const float2 sc = t_sc[NN + n];
            float h = acc[0][r] + sc.x * acc[1][r] + sc.y * acc[2][r] + b1o;
            h = fmaxf(h, 0.f);
            const int o = hf * 16 + m15;
            const u16 hi = f2bf(h);
            hHi[sl2 * 40 + o] = hi;
            hLo[sl2 * 40 + o] = f2bf(h - bf2f(hi));
            h32[sl2 * 33 + o] = h;
        }
        __syncthreads();

        // ---- phase 3: tcn1 via MFMA + Wout lane-reduce (R4 exact) ----
        f32x4 c2 = (f32x4){0.f, 0.f, 0.f, 0.f};
        {
            const bf16x8 ahh = *(const bf16x8*)&hHi[(st2 * 16 + m15) * 40 + q * 8];
            const bf16x8 ahl = *(const bf16x8*)&hLo[(st2 * 16 + m15) * 40 + q * 8];
            c2 = __builtin_amdgcn_mfma_f32_16x16x32_bf16(ahh, bwh, c2, 0, 0, 0);
            c2 = __builtin_amdgcn_mfma_f32_16x16x32_bf16(ahh, bwl, c2, 0, 0, 0);
            c2 = __builtin_amdgcn_mfma_f32_16x16x32_bf16(ahl, bwh, c2, 0, 0, 0);
        }
        float p[4];
        #pragma unroll
        for (int r = 0; r < 4; ++r) {
            const int sl2 = st2 * 16 + q * 4 + r;
            const float hres = h32[sl2 * 33 + ot * 16 + m15];
            float yv = tanhf(c2[r] + bt1o + hres);
            yv = fmaxf(yv, 0.f);
            p[r] = yv * wouto;
            #pragma unroll
            for (int mk = 1; mk <= 8; mk <<= 1)
                p[r] += __shfl_xor(p[r], mk, 64);
        }
        float selv  = (m15 & 1) ? p[1] : p[0];
        float selv2 = (m15 & 1) ? p[3] : p[2];
        selv = (m15 & 2) ? selv2 : selv;
        if (m15 < 4) sPart[ot * 32 + st2 * 16 + q * 4 + m15] = selv;
        __syncthreads();

        if (tid < 32) out[sbase + tid] = sPart[tid] + sPart[32 + tid] + boutv;
        // no trailing sync (R4-validated): next macro's LDS writes are to
        // uSpace, whose readers (phase-3 h reads) precede the sync above;
        // sPart is rewritten only after 3 more syncs.
    }
}

// ---------------------------------------------------------------------------
extern "C" void kernel_launch(void* const* d_in, const int* in_sizes, int n_in,
                              void* d_out, int out_size, void* d_ws, size_t ws_size,
                              hipStream_t stream)
{
    const float* X      = (const float*)d_in[0];
    const float* adj    = (const float*)d_in[1];
    const float* adjm   = (const float*)d_in[2];
    const float* Theta0 = (const float*)d_in[3];
    const float* bias0  = (const float*)d_in[4];
    const float* Wt0    = (const float*)d_in[5];
    const float* bt0    = (const float*)d_in[6];
    const float* Theta1 = (const float*)d_in[7];
    const float* bias1  = (const float*)d_in[8];
    const float* Wt1    = (const float*)d_in[9];
    const float* bt1    = (const float*)d_in[10];
    const float* Wout   = (const float*)d_in[11];
    const float* bout   = (const float*)d_in[12];
    (void)in_sizes; (void)n_in; (void)out_size; (void)ws_size;

    char* p = (char*)d_ws;
    int*    t_idx  = (int*)p;    p += (size_t)2 * NN * LISTCAP * sizeof(int);
    float*  t_val  = (float*)p;  p += (size_t)2 * NN * LISTCAP * sizeof(float);
    int*    t_cnt  = (int*)p;    p += (size_t)2 * NN * sizeof(int);
    float*  t_deg  = (float*)p;  p += (size_t)2 * NN * sizeof(float);
    float*  t_ideg = (float*)p;  p += (size_t)2 * NN * sizeof(float);
    float2* t_sc   = (float2*)p; p += (size_t)2 * NN * sizeof(float2);
    float*  I1     = (float*)p;  p += (size_t)NSITES * CC * sizeof(float);
    u16*    thHi   = (u16*)p;    p += (size_t)96 * 128 * sizeof(u16);
    u16*    thLo   = (u16*)p;    p += (size_t)96 * 128 * sizeof(u16);
    u16*    wtHi   = (u16*)p;    p += (size_t)1024 * sizeof(u16);
    u16*    wtLo   = (u16*)p;    p += (size_t)1024 * sizeof(u16);

    hipLaunchKernelGGL(topk_prep, dim3(2 * NN), dim3(256), 0, stream,
                       adj, adjm, t_idx, t_val, t_cnt, t_deg, t_ideg, t_sc);
    hipLaunchKernelGGL(stower0_tcn0, dim3(NSITES / 256 + 13), dim3(256), 0, stream,
                       X, t_idx, t_val, t_cnt, t_deg, Theta0, bias0, Wt0, bt0,
                       Theta1, Wt1, thHi, thLo, wtHi, wtLo, I1);
    hipLaunchKernelGGL(stower1_fused, dim3(NSITES / 96), dim3(256), 0, stream,
                       I1, t_idx, t_val, t_cnt, t_ideg,
                       thHi, thLo, wtHi, wtLo, t_sc,
                       bias1, bt1, Wout, bout, (float*)d_out);
}

// Round 3
// 172.710 us; speedup vs baseline: 1.0404x; 1.0404x over previous
//
#include <hip/hip_runtime.h>
#include <hip/hip_bf16.h>
#include <math.h>

#define BB 4
#define TT 12
#define NN 2000
#define KK 8
#define CC 32
#define EPSF 1e-5f
#define LISTCAP 16
#define NSITES (BB * TT * NN)   // 96000

typedef unsigned short u16;
typedef __bf16 bf16x8 __attribute__((ext_vector_type(8)));
typedef float  f32x4  __attribute__((ext_vector_type(4)));

__device__ __forceinline__ u16 f2bf(float x) {
    union { __hip_bfloat16 h; u16 u; } c;
    c.h = __float2bfloat16(x);   // RNE
    return c.u;
}
__device__ __forceinline__ float bf2f(u16 u) {
    return __uint_as_float(((unsigned)u) << 16);
}
__device__ __forceinline__ float mask6(float v) {
    if (isnan(v)) v = 6.0f;
    if (isinf(v)) v = 0.0f;
    return fminf(v, 6.0f);
}

// ---------------------------------------------------------------------------
// Kernel A (R12, validated): block-per-row, value-only 32-bit top-8.
// ---------------------------------------------------------------------------
__global__ __launch_bounds__(256)
void topk_prep(const float* __restrict__ adj, const float* __restrict__ adjm,
               int* __restrict__ t_idx, float* __restrict__ t_val,
               int* __restrict__ t_cnt, float* __restrict__ t_deg,
               float* __restrict__ t_ideg, float2* __restrict__ t_sc)
{
    __shared__ float sTop[4][8];
    __shared__ float sDeg[4];
    __shared__ int   sCp[4];
    __shared__ int   sStrictIdx[8];
    __shared__ float sStrictVal[8];
    __shared__ int   sTieIdx[16];
    __shared__ int   nStrict, nTie;
    __shared__ float sThr;

    const int tid  = threadIdx.x;
    const int lane = tid & 63;
    const int wid  = tid >> 6;

    const int grow = blockIdx.x;                    // 0..3999, one row per block
    const int mat = (grow >= NN) ? 1 : 0;           // 0 = adj_mask, 1 = adj
    const int row = grow - mat * NN;
    const float* src = (mat == 0 ? adjm : adj) + (size_t)row * NN;
    const float4* src4 = (const float4*)src;        // 500 float4 per row

    if (tid == 0) { nStrict = 0; nTie = 0; }

    // ---- load: 2 coalesced float4 per thread (2048 >= 2000 slots) ----
    const float4 v0 = src4[tid];                    // idx4 = tid < 500 always
    const float4 v1 = (tid < 244) ? src4[256 + tid]
                                  : make_float4(-1.f, -1.f, -1.f, -1.f);
    const float vv[8] = {v0.x, v0.y, v0.z, v0.w, v1.x, v1.y, v1.z, v1.w};

    // ---- per-lane sort-8 descending: Batcher 19-comparator network ----
    float a[8];
    #pragma unroll
    for (int j = 0; j < 8; ++j) a[j] = vv[j];
    #define CE(i, j) { float _mx = fmaxf(a[i], a[j]); float _mn = fminf(a[i], a[j]); a[i] = _mx; a[j] = _mn; }
    CE(0,1) CE(2,3) CE(4,5) CE(6,7)
    CE(0,2) CE(1,3) CE(4,6) CE(5,7)
    CE(1,2) CE(5,6)
    CE(0,4) CE(1,5) CE(2,6) CE(3,7)
    CE(2,4) CE(3,5)
    CE(1,2) CE(3,4) CE(5,6)
    #undef CE

    // ---- wave butterfly merge: 6 levels, 32-bit values ----
    float key[8];
    #pragma unroll
    for (int j = 0; j < 8; ++j) key[j] = a[j];
    #pragma unroll
    for (int d = 1; d < 64; d <<= 1) {
        float ok[8], c[8];
        #pragma unroll
        for (int j = 0; j < 8; ++j) ok[j] = __shfl_xor(key[j], d, 64);
        #pragma unroll
        for (int j = 0; j < 8; ++j) c[j] = fmaxf(key[j], ok[7 - j]);
        #pragma unroll
        for (int st = 4; st >= 1; st >>= 1) {
            #pragma unroll
            for (int j = 0; j < 8; ++j) {
                if ((j & st) == 0 && (j | st) < 8) {
                    float hi = fmaxf(c[j], c[j | st]);
                    float lo = fminf(c[j], c[j | st]);
                    c[j] = hi; c[j | st] = lo;
                }
            }
        }
        #pragma unroll
        for (int j = 0; j < 8; ++j) key[j] = c[j];
    }
    if (lane == 0) {
        #pragma unroll
        for (int j = 0; j < 8; ++j) sTop[wid][j] = key[j];
    }
    __syncthreads();

    // ---- thr: 4-way merge of sorted 8-lists, 8 steps (thread 0) ----
    if (tid == 0) {
        int p0 = 0, p1 = 0, p2 = 0, p3 = 0;
        float t = -1.f;
        for (int r = 0; r < 8; ++r) {
            const float c0 = (p0 < 8) ? sTop[0][p0] : -2.f;
            const float c1 = (p1 < 8) ? sTop[1][p1] : -2.f;
            const float c2 = (p2 < 8) ? sTop[2][p2] : -2.f;
            const float c3 = (p3 < 8) ? sTop[3][p3] : -2.f;
            float bv = c0; int best = 0;
            if (c1 > bv) { bv = c1; best = 1; }
            if (c2 > bv) { bv = c2; best = 2; }
            if (c3 > bv) { bv = c3; best = 3; }
            if (best == 0) ++p0; else if (best == 1) ++p1;
            else if (best == 2) ++p2; else ++p3;
            t = bv;
        }
        sThr = t;
    }
    __syncthreads();
    const float thr = sThr;

    // ---- pass 2: from registers. deg/cp over ALL v >= thr; collect set ----
    float degp = 0.f; int cp = 0;
    #pragma unroll
    for (int s = 0; s < 8; ++s) {
        const float v = vv[s];
        const int e = (s < 4) ? (tid * 4 + s) : ((256 + tid) * 4 + (s - 4));
        const bool ge = (v >= thr);
        degp += ge ? v : 0.f;
        cp   += (ge && v > 0.f) ? 1 : 0;
        if (v > thr) {                               // <= 7 per row
            int p = atomicAdd(&nStrict, 1);
            if (p < 8) { sStrictIdx[p] = e; sStrictVal[p] = v; }
        } else if (v == thr) {                       // ties (bit-exact equality)
            int p = atomicAdd(&nTie, 1);
            if (p < 16) sTieIdx[p] = e;
        }
    }
    #pragma unroll
    for (int off = 32; off >= 1; off >>= 1) {
        degp += __shfl_xor(degp, off, 64);
        cp   += __shfl_xor(cp, off, 64);
    }
    if (lane == 0) { sDeg[wid] = degp; sCp[wid] = cp; }
    __syncthreads();

    // ---- finalize (thread 0): lowest-index ties complete the top-8 set ----
    if (tid == 0) {
        const float deg = sDeg[0] + sDeg[1] + sDeg[2] + sDeg[3];
        const int cnt_pos = sCp[0] + sCp[1] + sCp[2] + sCp[3];
        int m = nStrict; if (m > 8) m = 8;           // mathematically <= 7
        int nt = nTie;   if (nt > 16) nt = 16;
        for (int i = 1; i < nt; ++i) {
            int v = sTieIdx[i]; int j = i - 1;
            while (j >= 0 && sTieIdx[j] > v) { sTieIdx[j + 1] = sTieIdx[j]; --j; }
            sTieIdx[j + 1] = v;
        }
        const size_t ob = (size_t)grow * LISTCAP;
        for (int j = 0; j < m; ++j) {
            t_idx[ob + j] = sStrictIdx[j];
            t_val[ob + j] = sStrictVal[j];
        }
        const int need = 8 - m;                      // >= 1; nt >= need always
        for (int j = 0; j < need; ++j) {
            t_idx[ob + m + j] = sTieIdx[j];
            t_val[ob + m + j] = thr;
        }
        int extra = nt - need;
        if (extra > 8) extra = 8; if (extra < 0) extra = 0;
        for (int j = 0; j < extra; ++j) {
            t_idx[ob + 8 + j] = sTieIdx[need + j];
            t_val[ob + 8 + j] = thr;
        }
        t_cnt[grow]  = 8 + extra;
        t_deg[grow]  = deg;
        t_ideg[grow] = 1.0f / deg;
        const float s1 = log1pf((float)cnt_pos);
        t_sc[grow]   = make_float2(s1, 1.0f / s1);
    }
}

// ---------------------------------------------------------------------------
// Kernel B: stower0 + tcn0 (blocks 0..374) + weight-plane prep (375..387).
// Unchanged from R9 (validated; Theta planes pre-swizzled).
// ---------------------------------------------------------------------------
__global__ __launch_bounds__(256)
void stower0_tcn0(const float* __restrict__ X,
                  const int* __restrict__ t_idx, const float* __restrict__ t_val,
                  const int* __restrict__ t_cnt, const float* __restrict__ t_deg,
                  const float* __restrict__ Theta0, const float* __restrict__ bias0,
                  const float* __restrict__ Wt0, const float* __restrict__ bt0,
                  const float* __restrict__ Theta1, const float* __restrict__ Wt1,
                  u16* __restrict__ thHi, u16* __restrict__ thLo,
                  u16* __restrict__ wtHi, u16* __restrict__ wtLo,
                  float* __restrict__ I1)
{
    const int tid = threadIdx.x;
    if (blockIdx.x >= NSITES / 256) {
        const int pb = blockIdx.x - NSITES / 256;   // 0..12
        if (pb < 12) {                              // Theta1: 12288 elems
            const int base = pb * 1024;
            #pragma unroll
            for (int t = 0; t < 4; ++t) {
                const int i = base + t * 256 + tid;
                const int r = i >> 5, o = i & 31;
                const int jm = r >> 7, k = r & 127;
                const int tile = jm * 2 + (o >> 4), n = o & 15;
                const float v = Theta1[i];
                const u16 hi = f2bf(v);
                const int idx = (tile * 16 + n) * 128 + (((k >> 3) ^ n) << 3) + (k & 7);
                thHi[idx] = hi;
                thLo[idx] = f2bf(v - bf2f(hi));
            }
        } else {                                    // Wt1: 1024 elems
            #pragma unroll
            for (int t = 0; t < 4; ++t) {
                const int i = t * 256 + tid;
                const float v = Wt1[i];
                const u16 hi = f2bf(v);
                wtHi[i] = hi;
                wtLo[i] = f2bf(v - bf2f(hi));
            }
        }
        return;
    }

    const int site = blockIdx.x * 256 + tid;
    const int n  = site % NN;
    const int bt = site / NN;
    const float* xrow = X + (size_t)bt * NN;

    const size_t base = (size_t)n * LISTCAP;
    const int cnt   = t_cnt[n];
    const float deg = t_deg[n];
    float wsum = 0.f, wsq = 0.f, mx = -INFINITY, mn = INFINITY;
    for (int j = 0; j < cnt; ++j) {
        int   id = t_idx[base + j];
        float w  = t_val[base + j];
        float xv = xrow[id];
        wsum = fmaf(w, xv, wsum);
        wsq  = fmaf(w * xv, xv, wsq);
        if (j < KK && w > 0.f) { mx = fmaxf(mx, xv); mn = fminf(mn, xv); }
    }
    float mean = wsum / deg;
    float var  = wsq / deg - mean * mean;
    float sd   = sqrtf(fmaxf(var, 0.f) + EPSF);
    float m0 = mask6(mean), m1 = mask6(mx), m2 = mask6(mn), m3 = mask6(sd);

    float h0[CC];
    #pragma unroll
    for (int c = 0; c < CC; ++c) {
        float v = bias0[c];
        v = fmaf(m0, Theta0[0 * CC + c], v);
        v = fmaf(m1, Theta0[1 * CC + c], v);
        v = fmaf(m2, Theta0[2 * CC + c], v);
        v = fmaf(m3, Theta0[3 * CC + c], v);
        h0[c] = v;
    }
    float* op = I1 + (size_t)site * CC;
    #pragma unroll
    for (int c = 0; c < CC; ++c) {
        float acc = bt0[c] + h0[c];
        #pragma unroll
        for (int k = 0; k < CC; ++k) acc = fmaf(Wt0[c * CC + k], h0[k], acc);
        op[c] = tanhf(acc);
    }
}

// ---------------------------------------------------------------------------
// Kernel C (R14): fused stower1 agg + matmul + tcn1 + Wout, occupancy-tuned.
// R13 post-mortem: 44.8 us at Occupancy 19.7% — latency/barrier-bound with
// only 3 blocks/CU (LDS 48.5 KiB). R14 trims LDS to 32 KiB -> 4 blocks/CU:
//   * bH fragments loaded directly from global thHi (L2-hot 24 KiB), no
//     LDS staging, one init barrier removed;
//   * Theta-lo j3=2 tiles moved from sBlo into 16 VGPRs (sBlo 24->16 KiB);
//   * sPart folded into dead uSpace bytes [9472..9728] (h32 ends at 9344;
//     needs a trailing barrier per macro — added);
//   * __launch_bounds__(256,4) caps VGPR at 128 for 16 waves/CU;
//   * agg r-loop unroll 2 for gather-chain MLP.
// All arithmetic bit-identical to R13.
// ---------------------------------------------------------------------------
__global__ __launch_bounds__(256, 4)
void stower1_fused(const float* __restrict__ I1,
                   const int* __restrict__ t_idx, const float* __restrict__ t_val,
                   const int* __restrict__ t_cnt, const float* __restrict__ t_ideg,
                   const u16* __restrict__ thHi, const u16* __restrict__ thLo,
                   const u16* __restrict__ wtHi, const u16* __restrict__ wtLo,
                   const float2* __restrict__ t_sc,
                   const float* __restrict__ bias1, const float* __restrict__ bt1,
                   const float* __restrict__ Wout, const float* __restrict__ bout,
                   float* __restrict__ out)
{
    __shared__ u16 sBlo[64 * 128];                  // 16 KiB: Theta-lo tiles 0..3
    __shared__ alignas(16) u16 uSpace[8192];        // 16 KiB: m tile | h | sPart

    u16*   mT  = uSpace;                            // m tile: [0..4095]=hi, [4096..8191]=lo
    u16*   hHi = uSpace;                            // 32*40 u16
    u16*   hLo = hHi + 32 * 40;
    float* h32   = (float*)((char*)uSpace + 5120);  // 32*33 f32, ends at 9344
    float* sPart = (float*)((char*)uSpace + 9472);  // 64 f32, dead m-tile bytes

    const int tid  = threadIdx.x;
    const int lane = tid & 63;
    const int w    = tid >> 6;
    const int m15  = lane & 15;
    const int q    = lane >> 4;
    const int hf   = w & 1;          // phase-2 out-channel half
    const int st   = w >> 1;         // phase-2 site-tile 0..1
    const int ot   = w >> 1;         // phase-3 tcn out-tile
    const int st2  = w & 1;          // phase-3 site-tile

    // agg-phase role: group g (8 groups of 32) x feature f
    const int ag = tid >> 5;
    const int af = tid & 31;
    const int afh = af >> 3, afl = af & 7;

    // ---- init: B fragments direct from global (L2-hot); thLo tiles 0..3
    //      to LDS; j3=2 lo tiles to registers; scalars. No barriers here:
    //      the phase-1' -> phase-2 barrier orders sBlo for all readers. ----
    bf16x8 bH[3][4];
    #pragma unroll
    for (int j3 = 0; j3 < 3; ++j3) {
        const int tile = 2 * j3 + hf;
        #pragma unroll
        for (int ks = 0; ks < 4; ++ks)
            bH[j3][ks] = *(const bf16x8*)&thHi[(tile * 16 + m15) * 128 +
                                               (((ks * 4 + q) ^ m15) << 3)];
    }
    bf16x8 bL2[4];
    #pragma unroll
    for (int ks = 0; ks < 4; ++ks)
        bL2[ks] = *(const bf16x8*)&thLo[((4 + hf) * 16 + m15) * 128 +
                                        (((ks * 4 + q) ^ m15) << 3)];
    for (int i = tid; i < 1024; i += 256)
        ((float4*)sBlo)[i] = ((const float4*)thLo)[i];   // rows 0..63
    const bf16x8 bwh = *(const bf16x8*)&wtHi[(ot * 16 + m15) * 32 + q * 8];
    const bf16x8 bwl = *(const bf16x8*)&wtLo[(ot * 16 + m15) * 32 + q * 8];
    const float b1o   = bias1[hf * 16 + m15];
    const float bt1o  = bt1[ot * 16 + m15];
    const float wouto = Wout[ot * 16 + m15];
    const float boutv = bout[0];

    #pragma unroll 1
    for (int mb = 0; mb < 3; ++mb) {
        const int sbase = (blockIdx.x * 3 + mb) * 32;

        // ---- phase 1': aggregate 32 sites directly into LDS m tile ----
        #pragma unroll 2
        for (int r = 0; r < 4; ++r) {
            const int sl2  = ag * 4 + r;            // 0..31
            const int site = sbase + sl2;
            const int n    = site % NN;
            const int bt   = site / NN;
            const size_t rbase = (size_t)(NN + n) * LISTCAP;
            const int cnt    = t_cnt[NN + n];
            const float ideg = t_ideg[NN + n];
            const float* Ibt = I1 + (size_t)bt * NN * CC;

            const int4   i0 = *(const int4*)&t_idx[rbase];
            const int4   i1 = *(const int4*)&t_idx[rbase + 4];
            const float4 w0 = *(const float4*)&t_val[rbase];
            const float4 w1 = *(const float4*)&t_val[rbase + 4];

            const float x0 = Ibt[i0.x * CC + af];
            const float x1 = Ibt[i0.y * CC + af];
            const float x2 = Ibt[i0.z * CC + af];
            const float x3 = Ibt[i0.w * CC + af];
            const float x4 = Ibt[i1.x * CC + af];
            const float x5 = Ibt[i1.y * CC + af];
            const float x6 = Ibt[i1.z * CC + af];
            const float x7 = Ibt[i1.w * CC + af];

            float wsum = 0.f, wsq = 0.f, mx = -INFINITY, mn = INFINITY;
            #define AGG(wv, xv) do { \
                wsum = fmaf(wv, xv, wsum); wsq = fmaf(wv * xv, xv, wsq); \
                mx = fmaxf(mx, xv); mn = fminf(mn, xv); } while (0)
            AGG(w0.x, x0); AGG(w0.y, x1); AGG(w0.z, x2); AGG(w0.w, x3);
            AGG(w1.x, x4); AGG(w1.y, x5); AGG(w1.z, x6); AGG(w1.w, x7);
            #undef AGG
            if (cnt > 8) {                    // tie extras: ~never taken
                for (int j = 8; j < cnt; ++j) {
                    int   id = t_idx[rbase + j];
                    float wv = t_val[rbase + j];
                    float xv = Ibt[id * CC + af];
                    wsum = fmaf(wv, xv, wsum);
                    wsq  = fmaf(wv * xv, xv, wsq);
                }
            }
            const float mean = wsum * ideg;
            const float var  = wsq * ideg - mean * mean;
            const float sd   = sqrtf(fmaxf(var, 0.f) + EPSF);

            const int sx = sl2 & 15;                // == site & 15 (sbase%32==0)
            const int b  = sl2 * 128;
            const int ia  = b + (((0  + afh) ^ sx) << 3) + afl;   // k = f
            const int ib  = b + (((4  + afh) ^ sx) << 3) + afl;   // k = 32+f
            const int ic  = b + (((8  + afh) ^ sx) << 3) + afl;   // k = 64+f
            const int id_ = b + (((12 + afh) ^ sx) << 3) + afl;   // k = 96+f
            u16 h0 = f2bf(mean); mT[ia]  = h0; mT[4096 + ia]  = f2bf(mean - bf2f(h0));
            u16 h1 = f2bf(mx);   mT[ib]  = h1; mT[4096 + ib]  = f2bf(mx   - bf2f(h1));
            u16 h2 = f2bf(mn);   mT[ic]  = h2; mT[4096 + ic]  = f2bf(mn   - bf2f(h2));
            u16 h3 = f2bf(sd);   mT[id_] = h3; mT[4096 + id_] = f2bf(sd   - bf2f(h3));
        }
        __syncthreads();

        // ---- phase 2: MFMA (A from LDS m tile; B hi/lo2 regs, lo01 LDS) ----
        f32x4 acc[3];
        #pragma unroll
        for (int j3 = 0; j3 < 3; ++j3) acc[j3] = (f32x4){0.f, 0.f, 0.f, 0.f};
        const int arow = (st * 16 + m15) * 128;
        #pragma unroll
        for (int ks = 0; ks < 4; ++ks) {
            const int koff = (((ks * 4 + q) ^ m15) << 3);
            const bf16x8 aH = *(const bf16x8*)&mT[arow + koff];
            const bf16x8 aL = *(const bf16x8*)&mT[4096 + arow + koff];
            #pragma unroll
            for (int j3 = 0; j3 < 3; ++j3) {
                const bf16x8 bL = (j3 < 2)
                    ? *(const bf16x8*)&sBlo[((2 * j3 + hf) * 16 + m15) * 128 + koff]
                    : bL2[ks];
                acc[j3] = __builtin_amdgcn_mfma_f32_16x16x32_bf16(aH, bH[j3][ks], acc[j3], 0, 0, 0);
                acc[j3] = __builtin_amdgcn_mfma_f32_16x16x32_bf16(aH, bL,          acc[j3], 0, 0, 0);
                acc[j3] = __builtin_amdgcn_mfma_f32_16x16x32_bf16(aL, bH[j3][ks], acc[j3], 0, 0, 0);
            }
        }
        __syncthreads();   // all m-tile reads done -> safe to alias h

        // ---- combine scalers -> h (split-bf16 + f32 residual) ----
        #pragma unroll
        for (int r = 0; r < 4; ++r) {
            const int sl2  = st * 16 + q * 4 + r;
            const int site = sbase + sl2;
            const int n    = site % NN;
            const float2 sc = t_sc[NN + n];
            float h = acc[0][r] + sc.x * acc[1][r] + sc.y * acc[2][r] + b1o;
            h = fmaxf(h, 0.f);
            const int o = hf * 16 + m15;
            const u16 hi = f2bf(h);
            hHi[sl2 * 40 + o] = hi;
            hLo[sl2 * 40 + o] = f2bf(h - bf2f(hi));
            h32[sl2 * 33 + o] = h;
        }
        __syncthreads();

        // ---- phase 3: tcn1 via MFMA + Wout lane-reduce (R4 exact) ----
        f32x4 c2 = (f32x4){0.f, 0.f, 0.f, 0.f};
        {
            const bf16x8 ahh = *(const bf16x8*)&hHi[(st2 * 16 + m15) * 40 + q * 8];
            const bf16x8 ahl = *(const bf16x8*)&hLo[(st2 * 16 + m15) * 40 + q * 8];
            c2 = __builtin_amdgcn_mfma_f32_16x16x32_bf16(ahh, bwh, c2, 0, 0, 0);
            c2 = __builtin_amdgcn_mfma_f32_16x16x32_bf16(ahh, bwl, c2, 0, 0, 0);
            c2 = __builtin_amdgcn_mfma_f32_16x16x32_bf16(ahl, bwh, c2, 0, 0, 0);
        }
        float p[4];
        #pragma unroll
        for (int r = 0; r < 4; ++r) {
            const int sl2 = st2 * 16 + q * 4 + r;
            const float hres = h32[sl2 * 33 + ot * 16 + m15];
            float yv = tanhf(c2[r] + bt1o + hres);
            yv = fmaxf(yv, 0.f);
            p[r] = yv * wouto;
            #pragma unroll
            for (int mk = 1; mk <= 8; mk <<= 1)
                p[r] += __shfl_xor(p[r], mk, 64);
        }
        float selv  = (m15 & 1) ? p[1] : p[0];
        float selv2 = (m15 & 1) ? p[3] : p[2];
        selv = (m15 & 2) ? selv2 : selv;
        if (m15 < 4) sPart[ot * 32 + st2 * 16 + q * 4 + m15] = selv;
        __syncthreads();

        if (tid < 32) out[sbase + tid] = sPart[tid] + sPart[32 + tid] + boutv;
        __syncthreads();   // sPart aliases uSpace: next macro's agg writes
                           // must wait for the out-write reads above.
    }
}

// ---------------------------------------------------------------------------
extern "C" void kernel_launch(void* const* d_in, const int* in_sizes, int n_in,
                              void* d_out, int out_size, void* d_ws, size_t ws_size,
                              hipStream_t stream)
{
    const float* X      = (const float*)d_in[0];
    const float* adj    = (const float*)d_in[1];
    const float* adjm   = (const float*)d_in[2];
    const float* Theta0 = (const float*)d_in[3];
    const float* bias0  = (const float*)d_in[4];
    const float* Wt0    = (const float*)d_in[5];
    const float* bt0    = (const float*)d_in[6];
    const float* Theta1 = (const float*)d_in[7];
    const float* bias1  = (const float*)d_in[8];
    const float* Wt1    = (const float*)d_in[9];
    const float* bt1    = (const float*)d_in[10];
    const float* Wout   = (const float*)d_in[11];
    const float* bout   = (const float*)d_in[12];
    (void)in_sizes; (void)n_in; (void)out_size; (void)ws_size;

    char* p = (char*)d_ws;
    int*    t_idx  = (int*)p;    p += (size_t)2 * NN * LISTCAP * sizeof(int);
    float*  t_val  = (float*)p;  p += (size_t)2 * NN * LISTCAP * sizeof(float);
    int*    t_cnt  = (int*)p;    p += (size_t)2 * NN * sizeof(int);
    float*  t_deg  = (float*)p;  p += (size_t)2 * NN * sizeof(float);
    float*  t_ideg = (float*)p;  p += (size_t)2 * NN * sizeof(float);
    float2* t_sc   = (float2*)p; p += (size_t)2 * NN * sizeof(float2);
    float*  I1     = (float*)p;  p += (size_t)NSITES * CC * sizeof(float);
    u16*    thHi   = (u16*)p;    p += (size_t)96 * 128 * sizeof(u16);
    u16*    thLo   = (u16*)p;    p += (size_t)96 * 128 * sizeof(u16);
    u16*    wtHi   = (u16*)p;    p += (size_t)1024 * sizeof(u16);
    u16*    wtLo   = (u16*)p;    p += (size_t)1024 * sizeof(u16);

    hipLaunchKernelGGL(topk_prep, dim3(2 * NN), dim3(256), 0, stream,
                       adj, adjm, t_idx, t_val, t_cnt, t_deg, t_ideg, t_sc);
    hipLaunchKernelGGL(stower0_tcn0, dim3(NSITES / 256 + 13), dim3(256), 0, stream,
                       X, t_idx, t_val, t_cnt, t_deg, Theta0, bias0, Wt0, bt0,
                       Theta1, Wt1, thHi, thLo, wtHi, wtLo, I1);
    hipLaunchKernelGGL(stower1_fused, dim3(NSITES / 96), dim3(256), 0, stream,
                       I1, t_idx, t_val, t_cnt, t_ideg,
                       thHi, thLo, wtHi, wtLo, t_sc,
                       bias1, bt1, Wout, bout, (float*)d_out);
}